// Round 1
// baseline (231.789 us; speedup 1.0000x reference)
//
#include <hip/hip_runtime.h>
#include <hip/hip_bf16.h>

#define S_LEN 2048
#define NHQ 32
#define NHKV 8
#define GRP 4
#define DH 128
#define QTILE 64
#define KTILE 32
#define KS_PITCH 136
#define PS_PITCH 40

typedef float f32x4 __attribute__((ext_vector_type(4)));
typedef short bf16x8 __attribute__((ext_vector_type(8)));
typedef float float4_t __attribute__((ext_vector_type(4)));

__device__ __forceinline__ unsigned short f2bf(float f) {
  union { float f; unsigned int u; } x;
  x.f = f;
  unsigned int r = x.u + 0x7fffu + ((x.u >> 16) & 1u);
  return (unsigned short)(r >> 16);
}

__device__ __forceinline__ bf16x8 pack8(float4_t a, float4_t b) {
  bf16x8 f;
  f[0] = (short)f2bf(a[0]); f[1] = (short)f2bf(a[1]);
  f[2] = (short)f2bf(a[2]); f[3] = (short)f2bf(a[3]);
  f[4] = (short)f2bf(b[0]); f[5] = (short)f2bf(b[1]);
  f[6] = (short)f2bf(b[2]); f[7] = (short)f2bf(b[3]);
  return f;
}

__global__ __launch_bounds__(256) void attn_fwd(
    const float* __restrict__ Q, const float* __restrict__ K,
    const float* __restrict__ V, float* __restrict__ O) {
  __shared__ unsigned short Ks[KTILE * KS_PITCH];   // [k][d] bf16, padded
  __shared__ unsigned short Vt[DH * KTILE];         // [d][k] bf16, XOR-swizzled
  __shared__ unsigned short Ps[4][16 * PS_PITCH];   // per-wave P, padded

  const int bid = blockIdx.x;
  const int h = bid % NHQ;
  const int qt = (S_LEN / QTILE - 1) - bid / NHQ;   // heavy tiles first
  const int kvh = h >> 2;                           // GQA: h = kvh*4 + g
  const int q0 = qt * QTILE;
  const int tid = threadIdx.x;
  const int wid = tid >> 6;
  const int lane = tid & 63;
  const int l15 = lane & 15;
  const int l4 = lane >> 4;
  const int qw = q0 + wid * 16;                     // this wave's first q row

  // scale * log2(e): softmax computed in exp2 domain (invariant under base change)
  const float kscale = 0.08838834764831845f * 1.44269504088896340f;

  // ---- hoist Q fragments: A-frag lane layout: row=l&15, k = (l>>4)*8 + j ----
  bf16x8 qf[4];
  {
    const float* qp = Q + ((size_t)(qw + l15) * NHQ + h) * DH;
#pragma unroll
    for (int dc = 0; dc < 4; ++dc) {
      int d = dc * 32 + l4 * 8;
      float4_t a = *(const float4_t*)(qp + d);
      float4_t b = *(const float4_t*)(qp + d + 4);
      qf[dc] = pack8(a, b);
    }
  }

  f32x4 o[8];
#pragma unroll
  for (int i = 0; i < 8; ++i) o[i] = (f32x4){0.f, 0.f, 0.f, 0.f};
  float mrow[4] = {-1e30f, -1e30f, -1e30f, -1e30f};
  float lrow[4] = {0.f, 0.f, 0.f, 0.f};  // lane-local partial row sums

  const int ntile = qt * 2 + 2;  // causal: keys 0 .. q0+63
  for (int t = 0; t < ntile; ++t) {
    const int kv0 = t * KTILE;
    __syncthreads();  // previous tile's LDS reads done before overwrite

    // ---- stage K tile [32][128] fp32 -> bf16 LDS, coalesced ----
#pragma unroll
    for (int i = 0; i < 2; ++i) {
      int c = tid + i * 256;
      int row = c >> 4;
      int col = (c & 15) * 8;
      const float* kp = K + ((size_t)(kv0 + row) * NHKV + kvh) * DH + col;
      float4_t a = *(const float4_t*)kp;
      float4_t b = *(const float4_t*)(kp + 4);
      *(bf16x8*)&Ks[row * KS_PITCH + col] = pack8(a, b);
    }
    // ---- stage V tile transposed: Vt[d][k], swizzle col = k ^ (((d>>2)&3)<<3) ----
#pragma unroll
    for (int i = 0; i < 4; ++i) {
      int c = tid + i * 256;
      int k = c >> 5;
      int d0 = (c & 31) * 4;
      const float* vp = V + ((size_t)(kv0 + k) * NHKV + kvh) * DH + d0;
      float4_t v = *(const float4_t*)vp;
#pragma unroll
      for (int j = 0; j < 4; ++j) {
        int d = d0 + j;
        int col = k ^ (((d >> 2) & 3) << 3);
        Vt[d * KTILE + col] = f2bf(v[j]);
      }
    }
    __syncthreads();

    if (kv0 <= qw + 15) {  // wave-uniform causal skip
      // ---- S = Q K^T, two 16-key halves, contraction over d in 4 chunks ----
      f32x4 s0 = {0.f, 0.f, 0.f, 0.f}, s1 = {0.f, 0.f, 0.f, 0.f};
#pragma unroll
      for (int dc = 0; dc < 4; ++dc) {
        bf16x8 k0 = *(const bf16x8*)&Ks[l15 * KS_PITCH + dc * 32 + l4 * 8];
        bf16x8 k1 = *(const bf16x8*)&Ks[(16 + l15) * KS_PITCH + dc * 32 + l4 * 8];
        s0 = __builtin_amdgcn_mfma_f32_16x16x32_bf16(qf[dc], k0, s0, 0, 0, 0);
        s1 = __builtin_amdgcn_mfma_f32_16x16x32_bf16(qf[dc], k1, s1, 0, 0, 0);
      }
      const bool needmask = (kv0 + KTILE - 1 > qw);  // wave-uniform
#pragma unroll
      for (int r = 0; r < 4; ++r) {
        float t0 = s0[r] * kscale;
        float t1 = s1[r] * kscale;
        if (needmask) {
          int qg = qw + l4 * 4 + r;  // C/D layout: row = (lane>>4)*4 + reg
          if (kv0 + l15 > qg) t0 = -1e30f;
          if (kv0 + 16 + l15 > qg) t1 = -1e30f;
        }
        // row max across the 16 lanes holding this row's 32 keys
        float mx = fmaxf(t0, t1);
        mx = fmaxf(mx, __shfl_xor(mx, 1, 16));
        mx = fmaxf(mx, __shfl_xor(mx, 2, 16));
        mx = fmaxf(mx, __shfl_xor(mx, 4, 16));
        mx = fmaxf(mx, __shfl_xor(mx, 8, 16));
        float mn = fmaxf(mrow[r], mx);
        float al = __builtin_amdgcn_exp2f(mrow[r] - mn);
        float p0 = __builtin_amdgcn_exp2f(t0 - mn);
        float p1 = __builtin_amdgcn_exp2f(t1 - mn);
        mrow[r] = mn;
        lrow[r] = lrow[r] * al + p0 + p1;
#pragma unroll
        for (int dt = 0; dt < 8; ++dt) o[dt][r] *= al;
        unsigned short* pw = &Ps[wid][(l4 * 4 + r) * PS_PITCH];
        pw[l15] = f2bf(p0);
        pw[16 + l15] = f2bf(p1);
      }
      // ---- O += P V : one A-frag (P 16x32), 8 d-tiles of V ----
      bf16x8 pa = *(const bf16x8*)&Ps[wid][l15 * PS_PITCH + l4 * 8];
#pragma unroll
      for (int dt = 0; dt < 8; ++dt) {
        int d = dt * 16 + l15;
        bf16x8 bv = *(const bf16x8*)&Vt[d * KTILE + ((l4 ^ ((l15 >> 2) & 3)) << 3)];
        o[dt] = __builtin_amdgcn_mfma_f32_16x16x32_bf16(pa, bv, o[dt], 0, 0, 0);
      }
    }
  }

  // ---- epilogue: reduce row sums across 16 lanes, normalize, store fp32 ----
#pragma unroll
  for (int r = 0; r < 4; ++r) {
    float s = lrow[r];
    s += __shfl_xor(s, 1, 16);
    s += __shfl_xor(s, 2, 16);
    s += __shfl_xor(s, 4, 16);
    s += __shfl_xor(s, 8, 16);
    float inv = 1.0f / s;
    int qg = qw + l4 * 4 + r;
    float* op = O + ((size_t)qg * NHQ + h) * DH;
#pragma unroll
    for (int dt = 0; dt < 8; ++dt) op[dt * 16 + l15] = o[dt][r] * inv;
  }
}

extern "C" void kernel_launch(void* const* d_in, const int* in_sizes, int n_in,
                              void* d_out, int out_size, void* d_ws, size_t ws_size,
                              hipStream_t stream) {
  const float* Q = (const float*)d_in[0];
  const float* K = (const float*)d_in[1];
  const float* V = (const float*)d_in[2];
  float* O = (float*)d_out;
  attn_fwd<<<dim3((S_LEN / QTILE) * NHQ), dim3(256), 0, stream>>>(Q, K, V, O);
}

// Round 2
// 225.159 us; speedup vs baseline: 1.0294x; 1.0294x over previous
//
#include <hip/hip_runtime.h>
#include <hip/hip_bf16.h>

#define S_LEN 2048
#define NHQ 32
#define NHKV 8
#define DH 128
#define KTILE 32
#define KS_PITCH 136   // ushorts; row stride 272B -> QK^T b128 reads ~uniform banks
#define VT_PITCH 40    // ushorts; row stride 80B = 20 dwords -> b128 R/W uniform banks
#define PS_PITCH 40

typedef float f32x4 __attribute__((ext_vector_type(4)));
typedef short bf16x8 __attribute__((ext_vector_type(8)));
typedef float float4_t __attribute__((ext_vector_type(4)));

__device__ __forceinline__ unsigned short f2bf(float f) {
  union { __hip_bfloat16 h; unsigned short u; } c;
  c.h = __float2bfloat16(f);
  return c.u;
}

__device__ __forceinline__ bf16x8 pack8(float4_t a, float4_t b) {
  bf16x8 f;
  f[0] = (short)f2bf(a[0]); f[1] = (short)f2bf(a[1]);
  f[2] = (short)f2bf(a[2]); f[3] = (short)f2bf(a[3]);
  f[4] = (short)f2bf(b[0]); f[5] = (short)f2bf(b[1]);
  f[6] = (short)f2bf(b[2]); f[7] = (short)f2bf(b[3]);
  return f;
}

__global__ __launch_bounds__(256, 2) void attn_fwd(
    const float* __restrict__ Q, const float* __restrict__ K,
    const float* __restrict__ V, float* __restrict__ O) {
  __shared__ unsigned short Ks[KTILE * KS_PITCH];   // [k][d] bf16
  __shared__ unsigned short Vt[DH * VT_PITCH];      // [d][k] bf16, pitch-40
  __shared__ unsigned short Ps[4][32 * PS_PITCH];   // per-wave P (32 q-rows)

  const int bid = blockIdx.x;
  const int kvh = bid & 7;            // XCD-locality: one KV-head per XCD
  const int qt = 63 - (bid >> 3);     // heavy q-tiles dispatched first
  const int q0 = qt * 32;
  const int tid = threadIdx.x;
  const int wid = tid >> 6;
  const int lane = tid & 63;
  const int l15 = lane & 15;
  const int l4 = lane >> 4;
  const int h = kvh * 4 + wid;        // wave = one q-head of this GQA group

  // softmax in exp2 domain: fold scale * log2(e)
  const float kscale = 0.08838834764831845f * 1.44269504088896340f;

  // ---- hoist Q: 2 row-tiles x 4 d-chunks; A-frag row=l&15, k=(l>>4)*8+j ----
  bf16x8 qf[2][4];
#pragma unroll
  for (int qr = 0; qr < 2; ++qr) {
    const float* qp = Q + ((size_t)(q0 + qr * 16 + l15) * NHQ + h) * DH;
#pragma unroll
    for (int dc = 0; dc < 4; ++dc) {
      float4_t a = *(const float4_t*)(qp + dc * 32 + l4 * 8);
      float4_t b = *(const float4_t*)(qp + dc * 32 + l4 * 8 + 4);
      qf[qr][dc] = pack8(a, b);
    }
  }

  f32x4 o[2][8];
#pragma unroll
  for (int qr = 0; qr < 2; ++qr)
#pragma unroll
    for (int dt = 0; dt < 8; ++dt) o[qr][dt] = (f32x4){0.f, 0.f, 0.f, 0.f};
  float mrow[8] = {-1e30f, -1e30f, -1e30f, -1e30f, -1e30f, -1e30f, -1e30f, -1e30f};
  float lrow[8] = {0.f, 0.f, 0.f, 0.f, 0.f, 0.f, 0.f, 0.f};

  // V staging role: thread owns one d (0..127), half the k-range (16 keys)
  const int vd = tid & 127;
  const int vkh = tid >> 7;  // 0 or 1
  const float* vbase = V + ((size_t)(vkh * 16) * NHKV + kvh) * DH + vd;

  const int ntile = qt + 1;  // causal: keys 0 .. q0+31; block-uniform
  for (int t = 0; t < ntile; ++t) {
    const int kv0 = t * KTILE;
    __syncthreads();  // previous tile's LDS reads done

    // ---- K tile [32][128] fp32 -> bf16 LDS, b128 writes, coalesced reads ----
#pragma unroll
    for (int i = 0; i < 2; ++i) {
      int c = tid + i * 256;
      int row = c >> 4;
      int col = (c & 15) * 8;
      const float* kp = K + ((size_t)(kv0 + row) * NHKV + kvh) * DH + col;
      float4_t a = *(const float4_t*)kp;
      float4_t b = *(const float4_t*)(kp + 4);
      *(bf16x8*)&Ks[row * KS_PITCH + col] = pack8(a, b);
    }
    // ---- V tile transposed via d-major global reads; 2x b128 LDS writes ----
    {
      const float* vp = vbase + (size_t)kv0 * (NHKV * DH);
      float v[16];
#pragma unroll
      for (int k = 0; k < 16; ++k) v[k] = vp[(size_t)k * (NHKV * DH)];
      bf16x8 a, b;
#pragma unroll
      for (int j = 0; j < 8; ++j) {
        a[j] = (short)f2bf(v[j]);
        b[j] = (short)f2bf(v[8 + j]);
      }
      *(bf16x8*)&Vt[vd * VT_PITCH + vkh * 16] = a;
      *(bf16x8*)&Vt[vd * VT_PITCH + vkh * 16 + 8] = b;
    }
    __syncthreads();

    // ---- S = Q K^T : 2 row-tiles x 2 key-halves, contract d in 4 chunks ----
    f32x4 s[2][2];
    s[0][0] = (f32x4){0.f, 0.f, 0.f, 0.f}; s[0][1] = (f32x4){0.f, 0.f, 0.f, 0.f};
    s[1][0] = (f32x4){0.f, 0.f, 0.f, 0.f}; s[1][1] = (f32x4){0.f, 0.f, 0.f, 0.f};
#pragma unroll
    for (int dc = 0; dc < 4; ++dc) {
      bf16x8 k0 = *(const bf16x8*)&Ks[l15 * KS_PITCH + dc * 32 + l4 * 8];
      bf16x8 k1 = *(const bf16x8*)&Ks[(16 + l15) * KS_PITCH + dc * 32 + l4 * 8];
      s[0][0] = __builtin_amdgcn_mfma_f32_16x16x32_bf16(qf[0][dc], k0, s[0][0], 0, 0, 0);
      s[0][1] = __builtin_amdgcn_mfma_f32_16x16x32_bf16(qf[0][dc], k1, s[0][1], 0, 0, 0);
      s[1][0] = __builtin_amdgcn_mfma_f32_16x16x32_bf16(qf[1][dc], k0, s[1][0], 0, 0, 0);
      s[1][1] = __builtin_amdgcn_mfma_f32_16x16x32_bf16(qf[1][dc], k1, s[1][1], 0, 0, 0);
    }

    const bool needmask = (t == ntile - 1);  // only diagonal tile masks
#pragma unroll
    for (int qr = 0; qr < 2; ++qr) {
#pragma unroll
      for (int r = 0; r < 4; ++r) {
        float t0 = s[qr][0][r] * kscale;
        float t1 = s[qr][1][r] * kscale;
        if (needmask) {
          int qg = qr * 16 + l4 * 4 + r;  // C/D layout: row=(lane>>4)*4+reg
          if (l15 > qg) t0 = -1e30f;
          if (16 + l15 > qg) t1 = -1e30f;
        }
        float mx = fmaxf(t0, t1);
        mx = fmaxf(mx, __shfl_xor(mx, 1, 16));
        mx = fmaxf(mx, __shfl_xor(mx, 2, 16));
        mx = fmaxf(mx, __shfl_xor(mx, 4, 16));
        mx = fmaxf(mx, __shfl_xor(mx, 8, 16));
        const int ri = qr * 4 + r;
        float mn = fmaxf(mrow[ri], mx);
        float al = __builtin_amdgcn_exp2f(mrow[ri] - mn);
        float p0 = __builtin_amdgcn_exp2f(t0 - mn);
        float p1 = __builtin_amdgcn_exp2f(t1 - mn);
        mrow[ri] = mn;
        lrow[ri] = lrow[ri] * al + p0 + p1;
#pragma unroll
        for (int dt = 0; dt < 8; ++dt) o[qr][dt][r] *= al;
        unsigned short* pw = &Ps[wid][(qr * 16 + l4 * 4 + r) * PS_PITCH];
        pw[l15] = f2bf(p0);
        pw[16 + l15] = f2bf(p1);
      }
    }

    // ---- O += P V : 2 P A-frags, 8 d-tiles of V (bv reused across qr) ----
    bf16x8 pa0 = *(const bf16x8*)&Ps[wid][l15 * PS_PITCH + l4 * 8];
    bf16x8 pa1 = *(const bf16x8*)&Ps[wid][(16 + l15) * PS_PITCH + l4 * 8];
#pragma unroll
    for (int dt = 0; dt < 8; ++dt) {
      bf16x8 bv = *(const bf16x8*)&Vt[(dt * 16 + l15) * VT_PITCH + l4 * 8];
      o[0][dt] = __builtin_amdgcn_mfma_f32_16x16x32_bf16(pa0, bv, o[0][dt], 0, 0, 0);
      o[1][dt] = __builtin_amdgcn_mfma_f32_16x16x32_bf16(pa1, bv, o[1][dt], 0, 0, 0);
    }
  }

  // ---- epilogue: reduce row sums across 16 lanes, normalize, store fp32 ----
#pragma unroll
  for (int qr = 0; qr < 2; ++qr) {
#pragma unroll
    for (int r = 0; r < 4; ++r) {
      const int ri = qr * 4 + r;
      float ssum = lrow[ri];
      ssum += __shfl_xor(ssum, 1, 16);
      ssum += __shfl_xor(ssum, 2, 16);
      ssum += __shfl_xor(ssum, 4, 16);
      ssum += __shfl_xor(ssum, 8, 16);
      float inv = 1.0f / ssum;
      int qg = q0 + qr * 16 + l4 * 4 + r;
      float* op = O + ((size_t)qg * NHQ + h) * DH;
#pragma unroll
      for (int dt = 0; dt < 8; ++dt) op[dt * 16 + l15] = o[qr][dt][r] * inv;
    }
  }
}

extern "C" void kernel_launch(void* const* d_in, const int* in_sizes, int n_in,
                              void* d_out, int out_size, void* d_ws, size_t ws_size,
                              hipStream_t stream) {
  const float* Q = (const float*)d_in[0];
  const float* K = (const float*)d_in[1];
  const float* V = (const float*)d_in[2];
  float* O = (float*)d_out;
  attn_fwd<<<dim3((S_LEN / 32) * NHKV), dim3(256), 0, stream>>>(Q, K, V, O);
}